// Round 5
// baseline (253.164 us; speedup 1.0000x reference)
//
#include <hip/hip_runtime.h>

// SpikeDrivenTransformer block, MI355X. T=4 B=16 C=512 H=W=16 (N=256), HEADS=8.
// ALL inputs/outputs fp32. Post-LIF tensors are binary -> conv1x1 = sparse
// column-sums over an active-channel list (scalarized via readfirstlane).
// R4: k2/k4 unroll-8 (MLP), k3 SWAR popcount rewrite, k5 float4 global I/O.

#define T_  4
#define B_  16
#define C_  512
#define N_  256
#define O3_ 1536
#define EPS_ 1e-5f

typedef unsigned int uint32;

// ---------------- k0: LDS-tiled weight transposes + BN folding ----------------
__global__ void k0_prep(const float* __restrict__ qw, const float* __restrict__ kw,
                        const float* __restrict__ vw, const float* __restrict__ pw,
                        const float* qg,const float* qb,const float* qm,const float* qv,
                        const float* kg,const float* kb,const float* km,const float* kvr,
                        const float* vg,const float* vb,const float* vm,const float* vv,
                        const float* pg,const float* pb2,const float* pm,const float* pv,
                        const float* projb,
                        float* __restrict__ wqkv_t, float* __restrict__ pwt,
                        float* __restrict__ bnc){
    __shared__ float tile[64 * 65];
    int bx = blockIdx.x, tid = threadIdx.x;
    if (bx < 256) {
        const float* src; float* dst; int ocol;
        int tl;
        if (bx < 192) { int g = bx / 64; tl = bx % 64;
            src = (g == 0) ? qw : (g == 1) ? kw : vw;
            dst = wqkv_t; ocol = g * 512;
        } else { tl = bx - 192; src = pw; dst = pwt; ocol = 0; }
        int o0 = (tl >> 3) * 64, c0 = (tl & 7) * 64;
        int dstride = (bx < 192) ? O3_ : C_;
        #pragma unroll
        for (int i = 0; i < 16; i++) {
            int idx = i * 256 + tid;
            int cl = idx & 63, ol = idx >> 6;      // lanes -> consecutive c (coalesced read)
            tile[ol * 65 + cl] = src[(size_t)(o0 + ol) * C_ + c0 + cl];
        }
        __syncthreads();
        #pragma unroll
        for (int i = 0; i < 16; i++) {
            int idx = i * 256 + tid;
            int ol = idx & 63, cl = idx >> 6;      // lanes -> consecutive o (coalesced write)
            dst[(size_t)(c0 + cl) * dstride + ocol + o0 + ol] = tile[ol * 65 + cl];
        }
    } else {
        int ch = (bx - 256) * 256 + tid;
        if (ch < C_) {
            {   float inv = qg[ch] / sqrtf(qv[ch] + EPS_);
                bnc[ch] = inv;            bnc[512 + ch]  = qb[ch] - qm[ch] * inv; }
            {   float inv = kg[ch] / sqrtf(kvr[ch] + EPS_);
                bnc[1024 + ch] = inv;     bnc[1536 + ch] = kb[ch] - km[ch] * inv; }
            {   float inv = vg[ch] / sqrtf(vv[ch] + EPS_);
                bnc[2048 + ch] = inv;     bnc[2560 + ch] = vb[ch] - vm[ch] * inv; }
            {   float inv = pg[ch] / sqrtf(pv[ch] + EPS_);
                float shift = pb2[ch] - pm[ch] * inv;
                bnc[3072 + ch] = inv;     bnc[3584 + ch] = projb[ch] * inv + shift; }
        }
    }
}

// ---------------- k1: LIF(x) + transpose-pack ----------------
// grid (B, C/64, N/64), block 256. xs_mask[b][n][c] byte holds 4 t-bits.
__global__ void k1_lif_x(const float* __restrict__ x, unsigned char* __restrict__ xs_mask){
    __shared__ unsigned char sm[64 * 68];
    int b = blockIdx.x, c0 = blockIdx.y * 64, n0 = blockIdx.z * 64;
    int tid = threadIdx.x;
    #pragma unroll
    for (int i = 0; i < 16; i++) {
        int idx = i * 256 + tid;
        int nl = idx & 63, cl = idx >> 6;          // lanes -> consecutive n (coalesced)
        const float* xp = x + ((size_t)b * C_ + c0 + cl) * N_ + n0 + nl;
        float v = 0.f; unsigned m = 0;
        #pragma unroll
        for (int t = 0; t < T_; t++) {
            float xt = xp[(size_t)t * B_ * C_ * N_];
            v = v + (xt - v) * 0.5f;               // v += (x - v)/TAU, TAU=2
            if (v - 1.0f >= 0.f) { m |= 1u << t; v = 0.f; }
        }
        sm[cl * 68 + nl] = (unsigned char)m;
    }
    __syncthreads();
    #pragma unroll
    for (int i = 0; i < 16; i++) {
        int idx = i * 256 + tid;
        int cl = idx & 63, nl = idx >> 6;          // lanes -> consecutive c (coalesced)
        xs_mask[((size_t)b * N_ + n0 + nl) * C_ + c0 + cl] = sm[cl * 68 + nl];
    }
}

// ---------------- k2: sparse qkv GEMM + BN + LIF ----------------
// grid (N, B), block 384. Thread tid: group g=tid>>7 (q/k/v), owns 4 channels;
// one float4 per active row (384 lanes x 16B = full 6KB q|k|v row). Unroll 8.
__global__ __launch_bounds__(384) void
k2_qkv(const unsigned char* __restrict__ xs_mask,
       const float* __restrict__ wqkv_t,
       const float* __restrict__ bnc,
       unsigned char* __restrict__ q_mask,
       unsigned char* __restrict__ kvand_mask){
    __shared__ uint32 smask[128];                  // 512 bytes; reused as kbits buffer
    __shared__ uint32 scnt;
    __shared__ uint32 slist[512];
    int n = blockIdx.x, b = blockIdx.y, tid = threadIdx.x;
    size_t colbase = ((size_t)b * N_ + n) * C_;
    if (tid < 128) smask[tid] = reinterpret_cast<const uint32*>(xs_mask + colbase)[tid];
    if (tid == 0) scnt = 0;
    __syncthreads();
    if (tid < 256) {
        const unsigned char* smb = (const unsigned char*)smask;
        #pragma unroll
        for (int h = 0; h < 2; h++) {
            int c = tid + (h << 8);
            unsigned m = smb[c];
            if (m) { unsigned p = atomicAdd(&scnt, 1u); slist[p] = (unsigned)c | (m << 16); }
        }
    }
    __syncthreads();
    int cnt = scnt;

    int g = tid >> 7;                              // 0=q, 1=k, 2=v
    float acc[4][4];
    #pragma unroll
    for (int t = 0; t < 4; t++)
        #pragma unroll
        for (int i = 0; i < 4; i++) acc[t][i] = 0.f;

#define ACC4(t, w_) { acc[t][0]+=w_.x; acc[t][1]+=w_.y; acc[t][2]+=w_.z; acc[t][3]+=w_.w; }
#define K2MASK(u) { unsigned mm = e##u >> 16; \
        if (mm & 1u) ACC4(0, w##u)  if (mm & 2u) ACC4(1, w##u) \
        if (mm & 4u) ACC4(2, w##u)  if (mm & 8u) ACC4(3, w##u) }
    int j = 0;
    for (; j + 8 <= cnt; j += 8) {
        unsigned e0 = __builtin_amdgcn_readfirstlane(slist[j + 0]);
        unsigned e1 = __builtin_amdgcn_readfirstlane(slist[j + 1]);
        unsigned e2 = __builtin_amdgcn_readfirstlane(slist[j + 2]);
        unsigned e3 = __builtin_amdgcn_readfirstlane(slist[j + 3]);
        unsigned e4 = __builtin_amdgcn_readfirstlane(slist[j + 4]);
        unsigned e5 = __builtin_amdgcn_readfirstlane(slist[j + 5]);
        unsigned e6 = __builtin_amdgcn_readfirstlane(slist[j + 6]);
        unsigned e7 = __builtin_amdgcn_readfirstlane(slist[j + 7]);
        float4 w0 = reinterpret_cast<const float4*>(wqkv_t + (size_t)(e0 & 0xffffu) * O3_)[tid];
        float4 w1 = reinterpret_cast<const float4*>(wqkv_t + (size_t)(e1 & 0xffffu) * O3_)[tid];
        float4 w2 = reinterpret_cast<const float4*>(wqkv_t + (size_t)(e2 & 0xffffu) * O3_)[tid];
        float4 w3 = reinterpret_cast<const float4*>(wqkv_t + (size_t)(e3 & 0xffffu) * O3_)[tid];
        float4 w4 = reinterpret_cast<const float4*>(wqkv_t + (size_t)(e4 & 0xffffu) * O3_)[tid];
        float4 w5 = reinterpret_cast<const float4*>(wqkv_t + (size_t)(e5 & 0xffffu) * O3_)[tid];
        float4 w6 = reinterpret_cast<const float4*>(wqkv_t + (size_t)(e6 & 0xffffu) * O3_)[tid];
        float4 w7 = reinterpret_cast<const float4*>(wqkv_t + (size_t)(e7 & 0xffffu) * O3_)[tid];
        K2MASK(0) K2MASK(1) K2MASK(2) K2MASK(3)
        K2MASK(4) K2MASK(5) K2MASK(6) K2MASK(7)
    }
    for (; j < cnt; j++) {
        unsigned e0 = __builtin_amdgcn_readfirstlane(slist[j]);
        float4 w0 = reinterpret_cast<const float4*>(wqkv_t + (size_t)(e0 & 0xffffu) * O3_)[tid];
        K2MASK(0)
    }
#undef K2MASK
#undef ACC4

    // BN + LIF per owned channel; pack 4 channel-bytes into one uint.
    int chb = (tid & 127) * 4;
    unsigned packed = 0;
    #pragma unroll
    for (int i = 0; i < 4; i++) {
        int ch = chb + i;
        float inv = bnc[g * 1024 + ch];
        float sh  = bnc[g * 1024 + 512 + ch];
        float v = 0.f; unsigned bits = 0;
        #pragma unroll
        for (int t = 0; t < 4; t++) {
            float pre = acc[t][i] * inv + sh;      // BN
            v = v + (pre - v) * 0.5f;              // LIF
            if (v - 1.0f >= 0.f) { bits |= 1u << t; v = 0.f; }
        }
        packed |= bits << (8 * i);
    }
    if (g == 0)      reinterpret_cast<uint32*>(q_mask + colbase)[tid] = packed;
    else if (g == 1) smask[tid - 128] = packed;    // kbits exchange
    __syncthreads();
    if (g == 2) {
        unsigned kb = smask[tid - 256];
        reinterpret_cast<uint32*>(kvand_mask + colbase)[tid - 256] = packed & kb;
    }
}

// ---------------- k3: kv SWAR popcount over n + exact LIF ----------------
// grid (B), block 256: 128 c4-lanes x 2 n-halves (128 n each). Coalesced uint32
// loads; per-byte packed counters (max 128 < 256, no carry).
__global__ void k3_kv(const uint32* __restrict__ kvand32,
                      unsigned char* __restrict__ kvs_mask){
    __shared__ uint32 part[4][128];
    int b = blockIdx.x, tid = threadIdx.x;
    int c4 = tid & 127, sub = tid >> 7;
    const uint32* p = kvand32 + (size_t)b * N_ * 128 + (size_t)sub * 128 * 128 + c4;
    uint32 cnt0 = 0, cnt1 = 0, cnt2 = 0, cnt3 = 0;
    for (int i = 0; i < 128; i++) {
        uint32 m = p[(size_t)i * 128];
        cnt0 +=  m        & 0x01010101u;
        cnt1 += (m >> 1)  & 0x01010101u;
        cnt2 += (m >> 2)  & 0x01010101u;
        cnt3 += (m >> 3)  & 0x01010101u;
    }
    if (sub == 1) { part[0][c4] = cnt0; part[1][c4] = cnt1; part[2][c4] = cnt2; part[3][c4] = cnt3; }
    __syncthreads();
    if (sub == 0) {
        uint32 o0 = part[0][c4], o1 = part[1][c4], o2 = part[2][c4], o3 = part[3][c4];
        unsigned outp = 0;
        #pragma unroll
        for (int e = 0; e < 4; e++) {
            int sh = 8 * e;
            float cn[4];
            cn[0] = (float)(int)(((cnt0 >> sh) & 0xffu) + ((o0 >> sh) & 0xffu));
            cn[1] = (float)(int)(((cnt1 >> sh) & 0xffu) + ((o1 >> sh) & 0xffu));
            cn[2] = (float)(int)(((cnt2 >> sh) & 0xffu) + ((o2 >> sh) & 0xffu));
            cn[3] = (float)(int)(((cnt3 >> sh) & 0xffu) + ((o3 >> sh) & 0xffu));
            float v = 0.f; unsigned bits = 0;
            #pragma unroll
            for (int t = 0; t < 4; t++) {
                v = v + (cn[t] - v) * 0.5f;        // exact (integer halvings)
                if (v - 0.5f >= 0.f) { bits |= 1u << t; v = 0.f; }
            }
            outp |= bits << sh;
        }
        reinterpret_cast<uint32*>(kvs_mask + (size_t)b * C_)[c4] = outp;
    }
}

// ---------------- k4: sparse proj GEMM (attn = q & kv_s) + BN ----------------
// grid (N, B), block 128. Thread owns 4 channels (float4 per 2KB row). Unroll 8.
__global__ __launch_bounds__(128) void
k4_attn_proj(const unsigned char* __restrict__ q_mask,
             const unsigned char* __restrict__ kvs_mask,
             const float* __restrict__ pwt,
             const float* __restrict__ bnc,
             float* __restrict__ y_t){
    __shared__ uint32 smask[128];
    __shared__ uint32 scnt;
    __shared__ uint32 slist[512];
    int n = blockIdx.x, b = blockIdx.y, tid = threadIdx.x;
    size_t colbase = ((size_t)b * N_ + n) * C_;
    {
        uint32 qm = reinterpret_cast<const uint32*>(q_mask + colbase)[tid];
        uint32 kv = reinterpret_cast<const uint32*>(kvs_mask + (size_t)b * C_)[tid];
        smask[tid] = qm & kv;
    }
    if (tid == 0) scnt = 0;
    __syncthreads();
    {
        const unsigned char* smb = (const unsigned char*)smask;
        #pragma unroll
        for (int h = 0; h < 4; h++) {
            int c = tid * 4 + h;
            unsigned m = smb[c];
            if (m) { unsigned p = atomicAdd(&scnt, 1u); slist[p] = (unsigned)c | (m << 16); }
        }
    }
    __syncthreads();
    int cnt = scnt;

    float acc[4][4];
    #pragma unroll
    for (int t = 0; t < 4; t++)
        #pragma unroll
        for (int i = 0; i < 4; i++) acc[t][i] = 0.f;

#define ACC4(t, w_) { acc[t][0]+=w_.x; acc[t][1]+=w_.y; acc[t][2]+=w_.z; acc[t][3]+=w_.w; }
#define K4MASK(u) { unsigned mm = e##u >> 16; \
        if (mm & 1u) ACC4(0, w##u)  if (mm & 2u) ACC4(1, w##u) \
        if (mm & 4u) ACC4(2, w##u)  if (mm & 8u) ACC4(3, w##u) }
    int j = 0;
    for (; j + 8 <= cnt; j += 8) {
        unsigned e0 = __builtin_amdgcn_readfirstlane(slist[j + 0]);
        unsigned e1 = __builtin_amdgcn_readfirstlane(slist[j + 1]);
        unsigned e2 = __builtin_amdgcn_readfirstlane(slist[j + 2]);
        unsigned e3 = __builtin_amdgcn_readfirstlane(slist[j + 3]);
        unsigned e4 = __builtin_amdgcn_readfirstlane(slist[j + 4]);
        unsigned e5 = __builtin_amdgcn_readfirstlane(slist[j + 5]);
        unsigned e6 = __builtin_amdgcn_readfirstlane(slist[j + 6]);
        unsigned e7 = __builtin_amdgcn_readfirstlane(slist[j + 7]);
        float4 w0 = reinterpret_cast<const float4*>(pwt + (size_t)(e0 & 0xffffu) * C_)[tid];
        float4 w1 = reinterpret_cast<const float4*>(pwt + (size_t)(e1 & 0xffffu) * C_)[tid];
        float4 w2 = reinterpret_cast<const float4*>(pwt + (size_t)(e2 & 0xffffu) * C_)[tid];
        float4 w3 = reinterpret_cast<const float4*>(pwt + (size_t)(e3 & 0xffffu) * C_)[tid];
        float4 w4 = reinterpret_cast<const float4*>(pwt + (size_t)(e4 & 0xffffu) * C_)[tid];
        float4 w5 = reinterpret_cast<const float4*>(pwt + (size_t)(e5 & 0xffffu) * C_)[tid];
        float4 w6 = reinterpret_cast<const float4*>(pwt + (size_t)(e6 & 0xffffu) * C_)[tid];
        float4 w7 = reinterpret_cast<const float4*>(pwt + (size_t)(e7 & 0xffffu) * C_)[tid];
        K4MASK(0) K4MASK(1) K4MASK(2) K4MASK(3)
        K4MASK(4) K4MASK(5) K4MASK(6) K4MASK(7)
    }
    for (; j < cnt; j++) {
        unsigned e0 = __builtin_amdgcn_readfirstlane(slist[j]);
        float4 w0 = reinterpret_cast<const float4*>(pwt + (size_t)(e0 & 0xffffu) * C_)[tid];
        K4MASK(0)
    }
#undef K4MASK
#undef ACC4

    float4 inv = reinterpret_cast<const float4*>(bnc + 3072)[tid];
    float4 sh  = reinterpret_cast<const float4*>(bnc + 3584)[tid];
    #pragma unroll
    for (int t = 0; t < 4; t++) {
        float4 y4;
        y4.x = acc[t][0] * inv.x + sh.x;
        y4.y = acc[t][1] * inv.y + sh.y;
        y4.z = acc[t][2] * inv.z + sh.z;
        y4.w = acc[t][3] * inv.w + sh.w;
        reinterpret_cast<float4*>(y_t + (((size_t)t * B_ + b) * N_ + n) * C_)[tid] = y4;
    }
}

// ---------------- k5: transpose back + identity add (float4 I/O) ----------------
// grid (B, C/64, N/64), block 256.
__global__ void k5_out(const float* __restrict__ y_t, const float* __restrict__ x,
                       float* __restrict__ out){
    __shared__ float tile[64 * 65];
    int b = blockIdx.x, o0 = blockIdx.y * 64, n0 = blockIdx.z * 64;
    int tid = threadIdx.x;
    for (int t = 0; t < T_; t++) {
        __syncthreads();
        #pragma unroll
        for (int i = 0; i < 4; i++) {
            int idx = i * 256 + tid;
            int o4 = idx & 15, nl = idx >> 4;      // lanes -> consecutive o (float4 read)
            float4 yv = *reinterpret_cast<const float4*>(
                y_t + (((size_t)t * B_ + b) * N_ + n0 + nl) * C_ + o0 + o4 * 4);
            tile[(o4 * 4 + 0) * 65 + nl] = yv.x;
            tile[(o4 * 4 + 1) * 65 + nl] = yv.y;
            tile[(o4 * 4 + 2) * 65 + nl] = yv.z;
            tile[(o4 * 4 + 3) * 65 + nl] = yv.w;
        }
        __syncthreads();
        #pragma unroll
        for (int i = 0; i < 4; i++) {
            int idx = i * 256 + tid;
            int n4 = idx & 15, ol = idx >> 4;      // lanes -> consecutive n (float4 write)
            size_t a = (((size_t)t * B_ + b) * C_ + o0 + ol) * N_ + n0 + n4 * 4;
            float4 xv = *reinterpret_cast<const float4*>(x + a);
            float4 yv;
            yv.x = tile[ol * 65 + n4 * 4 + 0] + xv.x;
            yv.y = tile[ol * 65 + n4 * 4 + 1] + xv.y;
            yv.z = tile[ol * 65 + n4 * 4 + 2] + xv.z;
            yv.w = tile[ol * 65 + n4 * 4 + 3] + xv.w;
            *reinterpret_cast<float4*>(out + a) = yv;
        }
    }
}

extern "C" void kernel_launch(void* const* d_in, const int* in_sizes, int n_in,
                              void* d_out, int out_size, void* d_ws, size_t ws_size,
                              hipStream_t stream){
    const float* x     = (const float*)d_in[0];
    const float* q_w   = (const float*)d_in[1];
    const float* q_g   = (const float*)d_in[2];
    const float* q_b   = (const float*)d_in[3];
    const float* q_m   = (const float*)d_in[4];
    const float* q_v   = (const float*)d_in[5];
    const float* k_w   = (const float*)d_in[6];
    const float* k_g   = (const float*)d_in[7];
    const float* k_b   = (const float*)d_in[8];
    const float* k_m   = (const float*)d_in[9];
    const float* k_v   = (const float*)d_in[10];
    const float* v_w   = (const float*)d_in[11];
    const float* v_g   = (const float*)d_in[12];
    const float* v_b   = (const float*)d_in[13];
    const float* v_m   = (const float*)d_in[14];
    const float* v_v   = (const float*)d_in[15];
    const float* pr_w  = (const float*)d_in[16];
    const float* pr_b  = (const float*)d_in[17];
    const float* p_g   = (const float*)d_in[18];
    const float* p_b2  = (const float*)d_in[19];
    const float* p_m   = (const float*)d_in[20];
    const float* p_v   = (const float*)d_in[21];
    float* out = (float*)d_out;

    char* ws = (char*)d_ws;
    float* wqkv_t          = (float*)(ws + 0);                 // 3,145,728
    float* pwt             = (float*)(ws + 3145728);           // 1,048,576
    float* bnc             = (float*)(ws + 4194304);           //    16,384
    unsigned char* xs_mask = (unsigned char*)(ws + 4210688);   // 2,097,152
    unsigned char* q_mask  = (unsigned char*)(ws + 6307840);   // 2,097,152
    unsigned char* kvand   = (unsigned char*)(ws + 8404992);   // 2,097,152
    unsigned char* kvs     = (unsigned char*)(ws + 10502144);  //     8,192
    float* y_t             = (float*)(ws + 10510336);          // 33,554,432 -> ~44 MB

    hipLaunchKernelGGL(k0_prep, dim3(258), dim3(256), 0, stream,
                       q_w, k_w, v_w, pr_w,
                       q_g,q_b,q_m,q_v, k_g,k_b,k_m,k_v, v_g,v_b,v_m,v_v,
                       p_g,p_b2,p_m,p_v, pr_b, wqkv_t, pwt, bnc);
    hipLaunchKernelGGL(k1_lif_x, dim3(B_, C_/64, N_/64), dim3(256), 0, stream, x, xs_mask);
    hipLaunchKernelGGL(k2_qkv, dim3(N_, B_), dim3(384), 0, stream,
                       xs_mask, wqkv_t, bnc, q_mask, kvand);
    hipLaunchKernelGGL(k3_kv, dim3(B_), dim3(256), 0, stream,
                       (const uint32*)kvand, kvs);
    hipLaunchKernelGGL(k4_attn_proj, dim3(N_, B_), dim3(128), 0, stream,
                       q_mask, kvs, pwt, bnc, y_t);
    hipLaunchKernelGGL(k5_out, dim3(B_, C_/64, N_/64), dim3(256), 0, stream, y_t, x, out);
}

// Round 6
// 212.367 us; speedup vs baseline: 1.1921x; 1.1921x over previous
//
#include <hip/hip_runtime.h>

// SpikeDrivenTransformer block, MI355X. T=4 B=16 C=512 H=W=16 (N=256), HEADS=8.
// ALL inputs/outputs fp32. Post-LIF tensors are binary -> conv1x1 = sparse
// column-sums over an active-channel list (scalarized via readfirstlane).
// R6: k2 reverted to unroll-4 (R4-proven; unroll-8 overflowed the 32-VGPR
// budget and serialized). k4 = 256 threads / 2 columns (4 waves/block).
// k1 float4 reads + packed uint32 writes. k3 SWAR + k5 float4 kept.

#define T_  4
#define B_  16
#define C_  512
#define N_  256
#define O3_ 1536
#define EPS_ 1e-5f

typedef unsigned int uint32;

// ---------------- k0: LDS-tiled weight transposes + BN folding ----------------
__global__ void k0_prep(const float* __restrict__ qw, const float* __restrict__ kw,
                        const float* __restrict__ vw, const float* __restrict__ pw,
                        const float* qg,const float* qb,const float* qm,const float* qv,
                        const float* kg,const float* kb,const float* km,const float* kvr,
                        const float* vg,const float* vb,const float* vm,const float* vv,
                        const float* pg,const float* pb2,const float* pm,const float* pv,
                        const float* projb,
                        float* __restrict__ wqkv_t, float* __restrict__ pwt,
                        float* __restrict__ bnc){
    __shared__ float tile[64 * 65];
    int bx = blockIdx.x, tid = threadIdx.x;
    if (bx < 256) {
        const float* src; float* dst; int ocol;
        int tl;
        if (bx < 192) { int g = bx / 64; tl = bx % 64;
            src = (g == 0) ? qw : (g == 1) ? kw : vw;
            dst = wqkv_t; ocol = g * 512;
        } else { tl = bx - 192; src = pw; dst = pwt; ocol = 0; }
        int o0 = (tl >> 3) * 64, c0 = (tl & 7) * 64;
        int dstride = (bx < 192) ? O3_ : C_;
        #pragma unroll
        for (int i = 0; i < 16; i++) {
            int idx = i * 256 + tid;
            int cl = idx & 63, ol = idx >> 6;      // lanes -> consecutive c (coalesced read)
            tile[ol * 65 + cl] = src[(size_t)(o0 + ol) * C_ + c0 + cl];
        }
        __syncthreads();
        #pragma unroll
        for (int i = 0; i < 16; i++) {
            int idx = i * 256 + tid;
            int ol = idx & 63, cl = idx >> 6;      // lanes -> consecutive o (coalesced write)
            dst[(size_t)(c0 + cl) * dstride + ocol + o0 + ol] = tile[ol * 65 + cl];
        }
    } else {
        int ch = (bx - 256) * 256 + tid;
        if (ch < C_) {
            {   float inv = qg[ch] / sqrtf(qv[ch] + EPS_);
                bnc[ch] = inv;            bnc[512 + ch]  = qb[ch] - qm[ch] * inv; }
            {   float inv = kg[ch] / sqrtf(kvr[ch] + EPS_);
                bnc[1024 + ch] = inv;     bnc[1536 + ch] = kb[ch] - km[ch] * inv; }
            {   float inv = vg[ch] / sqrtf(vv[ch] + EPS_);
                bnc[2048 + ch] = inv;     bnc[2560 + ch] = vb[ch] - vm[ch] * inv; }
            {   float inv = pg[ch] / sqrtf(pv[ch] + EPS_);
                float shift = pb2[ch] - pm[ch] * inv;
                bnc[3072 + ch] = inv;     bnc[3584 + ch] = projb[ch] * inv + shift; }
        }
    }
}

// ---------------- k1: LIF(x) + transpose-pack (float4 I/O) ----------------
// grid (B, C/64, N/64), block 256. Output uint32 = 4 consecutive-channel bytes.
__global__ void k1_lif_x(const float* __restrict__ x, uint32* __restrict__ xs_mask32){
    __shared__ uint32 sm32[64 * 17];               // [cl][nq], pitch 17
    int b = blockIdx.x, c0 = blockIdx.y * 64, n0 = blockIdx.z * 64;
    int tid = threadIdx.x;
    #pragma unroll
    for (int i = 0; i < 4; i++) {
        int idx = i * 256 + tid;
        int nq = idx & 15, cl = idx >> 4;          // lanes -> consecutive n-quads
        const float* xp = x + ((size_t)b * C_ + c0 + cl) * N_ + n0 + nq * 4;
        float4 xv[4];
        #pragma unroll
        for (int t = 0; t < 4; t++)
            xv[t] = *reinterpret_cast<const float4*>(xp + (size_t)t * B_ * C_ * N_);
        uint32 packed = 0;
        #pragma unroll
        for (int e = 0; e < 4; e++) {
            float v = 0.f; unsigned m = 0;
            #pragma unroll
            for (int t = 0; t < 4; t++) {
                float xt = reinterpret_cast<const float*>(&xv[t])[e];
                v = v + (xt - v) * 0.5f;           // v += (x - v)/TAU, TAU=2
                if (v - 1.0f >= 0.f) { m |= 1u << t; v = 0.f; }
            }
            packed |= m << (8 * e);
        }
        sm32[cl * 17 + nq] = packed;
    }
    __syncthreads();
    #pragma unroll
    for (int i = 0; i < 4; i++) {
        int idx = i * 256 + tid;
        int cq = idx & 15, nl = idx >> 4;          // lanes -> consecutive c-quads (coalesced)
        uint32 outp = 0;
        #pragma unroll
        for (int e = 0; e < 4; e++) {
            uint32 wv = sm32[(cq * 4 + e) * 17 + (nl >> 2)];
            outp |= ((wv >> (8 * (nl & 3))) & 0xffu) << (8 * e);
        }
        xs_mask32[((size_t)b * N_ + n0 + nl) * 128 + (c0 >> 2) + cq] = outp;
    }
}

// ---------------- k2: sparse qkv GEMM + BN + LIF (R4-proven, unroll-4) ----------------
// grid (N, B), block 384. Thread tid: group g=tid>>7 (q/k/v), owns 4 channels;
// one float4 per active row (384 lanes x 16B = full 6KB q|k|v row).
__global__ __launch_bounds__(384) void
k2_qkv(const unsigned char* __restrict__ xs_mask,
       const float* __restrict__ wqkv_t,
       const float* __restrict__ bnc,
       unsigned char* __restrict__ q_mask,
       unsigned char* __restrict__ kvand_mask){
    __shared__ uint32 smask[128];                  // 512 bytes; reused as kbits buffer
    __shared__ uint32 scnt;
    __shared__ uint32 slist[512];
    int n = blockIdx.x, b = blockIdx.y, tid = threadIdx.x;
    size_t colbase = ((size_t)b * N_ + n) * C_;
    if (tid < 128) smask[tid] = reinterpret_cast<const uint32*>(xs_mask + colbase)[tid];
    if (tid == 0) scnt = 0;
    __syncthreads();
    if (tid < 256) {
        const unsigned char* smb = (const unsigned char*)smask;
        #pragma unroll
        for (int h = 0; h < 2; h++) {
            int c = tid + (h << 8);
            unsigned m = smb[c];
            if (m) { unsigned p = atomicAdd(&scnt, 1u); slist[p] = (unsigned)c | (m << 16); }
        }
    }
    __syncthreads();
    int cnt = scnt;

    int g = tid >> 7;                              // 0=q, 1=k, 2=v
    float acc[4][4];
    #pragma unroll
    for (int t = 0; t < 4; t++)
        #pragma unroll
        for (int i = 0; i < 4; i++) acc[t][i] = 0.f;

#define ACC4(t, w_) { acc[t][0]+=w_.x; acc[t][1]+=w_.y; acc[t][2]+=w_.z; acc[t][3]+=w_.w; }
    int j = 0;
    for (; j + 4 <= cnt; j += 4) {
        unsigned e0 = __builtin_amdgcn_readfirstlane(slist[j]);
        unsigned e1 = __builtin_amdgcn_readfirstlane(slist[j + 1]);
        unsigned e2 = __builtin_amdgcn_readfirstlane(slist[j + 2]);
        unsigned e3 = __builtin_amdgcn_readfirstlane(slist[j + 3]);
        float4 w0 = reinterpret_cast<const float4*>(wqkv_t + (size_t)(e0 & 0xffffu) * O3_)[tid];
        float4 w1 = reinterpret_cast<const float4*>(wqkv_t + (size_t)(e1 & 0xffffu) * O3_)[tid];
        float4 w2 = reinterpret_cast<const float4*>(wqkv_t + (size_t)(e2 & 0xffffu) * O3_)[tid];
        float4 w3 = reinterpret_cast<const float4*>(wqkv_t + (size_t)(e3 & 0xffffu) * O3_)[tid];
        unsigned m0 = e0 >> 16, m1 = e1 >> 16, m2 = e2 >> 16, m3 = e3 >> 16;
        if (m0 & 1u) ACC4(0, w0)  if (m0 & 2u) ACC4(1, w0)
        if (m0 & 4u) ACC4(2, w0)  if (m0 & 8u) ACC4(3, w0)
        if (m1 & 1u) ACC4(0, w1)  if (m1 & 2u) ACC4(1, w1)
        if (m1 & 4u) ACC4(2, w1)  if (m1 & 8u) ACC4(3, w1)
        if (m2 & 1u) ACC4(0, w2)  if (m2 & 2u) ACC4(1, w2)
        if (m2 & 4u) ACC4(2, w2)  if (m2 & 8u) ACC4(3, w2)
        if (m3 & 1u) ACC4(0, w3)  if (m3 & 2u) ACC4(1, w3)
        if (m3 & 4u) ACC4(2, w3)  if (m3 & 8u) ACC4(3, w3)
    }
    for (; j < cnt; j++) {
        unsigned e0 = __builtin_amdgcn_readfirstlane(slist[j]);
        float4 w0 = reinterpret_cast<const float4*>(wqkv_t + (size_t)(e0 & 0xffffu) * O3_)[tid];
        unsigned m0 = e0 >> 16;
        if (m0 & 1u) ACC4(0, w0)  if (m0 & 2u) ACC4(1, w0)
        if (m0 & 4u) ACC4(2, w0)  if (m0 & 8u) ACC4(3, w0)
    }
#undef ACC4

    // BN + LIF per owned channel; pack 4 channel-bytes into one uint.
    int chb = (tid & 127) * 4;
    unsigned packed = 0;
    #pragma unroll
    for (int i = 0; i < 4; i++) {
        int ch = chb + i;
        float inv = bnc[g * 1024 + ch];
        float sh  = bnc[g * 1024 + 512 + ch];
        float v = 0.f; unsigned bits = 0;
        #pragma unroll
        for (int t = 0; t < 4; t++) {
            float pre = acc[t][i] * inv + sh;      // BN
            v = v + (pre - v) * 0.5f;              // LIF
            if (v - 1.0f >= 0.f) { bits |= 1u << t; v = 0.f; }
        }
        packed |= bits << (8 * i);
    }
    if (g == 0)      reinterpret_cast<uint32*>(q_mask + colbase)[tid] = packed;
    else if (g == 1) smask[tid - 128] = packed;    // kbits exchange
    __syncthreads();
    if (g == 2) {
        unsigned kb = smask[tid - 256];
        reinterpret_cast<uint32*>(kvand_mask + colbase)[tid - 256] = packed & kb;
    }
}

// ---------------- k3: kv SWAR popcount over n + exact LIF ----------------
// grid (B), block 256: 128 c4-lanes x 2 n-halves. Per-byte packed counters.
__global__ void k3_kv(const uint32* __restrict__ kvand32,
                      unsigned char* __restrict__ kvs_mask){
    __shared__ uint32 part[4][128];
    int b = blockIdx.x, tid = threadIdx.x;
    int c4 = tid & 127, sub = tid >> 7;
    const uint32* p = kvand32 + (size_t)b * N_ * 128 + (size_t)sub * 128 * 128 + c4;
    uint32 cnt0 = 0, cnt1 = 0, cnt2 = 0, cnt3 = 0;
    for (int i = 0; i < 128; i++) {
        uint32 m = p[(size_t)i * 128];
        cnt0 +=  m        & 0x01010101u;
        cnt1 += (m >> 1)  & 0x01010101u;
        cnt2 += (m >> 2)  & 0x01010101u;
        cnt3 += (m >> 3)  & 0x01010101u;
    }
    if (sub == 1) { part[0][c4] = cnt0; part[1][c4] = cnt1; part[2][c4] = cnt2; part[3][c4] = cnt3; }
    __syncthreads();
    if (sub == 0) {
        uint32 o0 = part[0][c4], o1 = part[1][c4], o2 = part[2][c4], o3 = part[3][c4];
        unsigned outp = 0;
        #pragma unroll
        for (int e = 0; e < 4; e++) {
            int sh = 8 * e;
            float cn[4];
            cn[0] = (float)(int)(((cnt0 >> sh) & 0xffu) + ((o0 >> sh) & 0xffu));
            cn[1] = (float)(int)(((cnt1 >> sh) & 0xffu) + ((o1 >> sh) & 0xffu));
            cn[2] = (float)(int)(((cnt2 >> sh) & 0xffu) + ((o2 >> sh) & 0xffu));
            cn[3] = (float)(int)(((cnt3 >> sh) & 0xffu) + ((o3 >> sh) & 0xffu));
            float v = 0.f; unsigned bits = 0;
            #pragma unroll
            for (int t = 0; t < 4; t++) {
                v = v + (cn[t] - v) * 0.5f;        // exact (integer halvings)
                if (v - 0.5f >= 0.f) { bits |= 1u << t; v = 0.f; }
            }
            outp |= bits << sh;
        }
        reinterpret_cast<uint32*>(kvs_mask + (size_t)b * C_)[c4] = outp;
    }
}

// ---------------- k4: sparse proj GEMM (attn = q & kv_s) + BN ----------------
// grid (N/2, B), block 256 = 2 columns x 128 threads (col = tid>>7, wave-uniform).
// Thread owns 4 channels (float4 per 2KB row), unroll-4.
__global__ __launch_bounds__(256) void
k4_attn_proj(const unsigned char* __restrict__ q_mask,
             const unsigned char* __restrict__ kvs_mask,
             const float* __restrict__ pwt,
             const float* __restrict__ bnc,
             float* __restrict__ y_t){
    __shared__ uint32 smask[2][128];
    __shared__ uint32 scnt[2];
    __shared__ uint32 slist[2][512];
    int b = blockIdx.y, tid = threadIdx.x;
    int col = tid >> 7, ctid = tid & 127;
    int n = blockIdx.x * 2 + col;
    size_t colbase = ((size_t)b * N_ + n) * C_;
    {
        uint32 qm = reinterpret_cast<const uint32*>(q_mask + colbase)[ctid];
        uint32 kv = reinterpret_cast<const uint32*>(kvs_mask + (size_t)b * C_)[ctid];
        smask[col][ctid] = qm & kv;
    }
    if (ctid == 0) scnt[col] = 0;
    __syncthreads();
    {
        const unsigned char* smb = (const unsigned char*)smask[col];
        #pragma unroll
        for (int h = 0; h < 4; h++) {
            int c = ctid * 4 + h;
            unsigned m = smb[c];
            if (m) { unsigned p = atomicAdd(&scnt[col], 1u); slist[col][p] = (unsigned)c | (m << 16); }
        }
    }
    __syncthreads();
    int cnt = scnt[col];
    const uint32* lst = slist[col];

    float acc[4][4];
    #pragma unroll
    for (int t = 0; t < 4; t++)
        #pragma unroll
        for (int i = 0; i < 4; i++) acc[t][i] = 0.f;

#define ACC4(t, w_) { acc[t][0]+=w_.x; acc[t][1]+=w_.y; acc[t][2]+=w_.z; acc[t][3]+=w_.w; }
    int j = 0;
    for (; j + 4 <= cnt; j += 4) {
        unsigned e0 = __builtin_amdgcn_readfirstlane(lst[j]);
        unsigned e1 = __builtin_amdgcn_readfirstlane(lst[j + 1]);
        unsigned e2 = __builtin_amdgcn_readfirstlane(lst[j + 2]);
        unsigned e3 = __builtin_amdgcn_readfirstlane(lst[j + 3]);
        float4 w0 = reinterpret_cast<const float4*>(pwt + (size_t)(e0 & 0xffffu) * C_)[ctid];
        float4 w1 = reinterpret_cast<const float4*>(pwt + (size_t)(e1 & 0xffffu) * C_)[ctid];
        float4 w2 = reinterpret_cast<const float4*>(pwt + (size_t)(e2 & 0xffffu) * C_)[ctid];
        float4 w3 = reinterpret_cast<const float4*>(pwt + (size_t)(e3 & 0xffffu) * C_)[ctid];
        unsigned m0 = e0 >> 16, m1 = e1 >> 16, m2 = e2 >> 16, m3 = e3 >> 16;
        if (m0 & 1u) ACC4(0, w0)  if (m0 & 2u) ACC4(1, w0)
        if (m0 & 4u) ACC4(2, w0)  if (m0 & 8u) ACC4(3, w0)
        if (m1 & 1u) ACC4(0, w1)  if (m1 & 2u) ACC4(1, w1)
        if (m1 & 4u) ACC4(2, w1)  if (m1 & 8u) ACC4(3, w1)
        if (m2 & 1u) ACC4(0, w2)  if (m2 & 2u) ACC4(1, w2)
        if (m2 & 4u) ACC4(2, w2)  if (m2 & 8u) ACC4(3, w2)
        if (m3 & 1u) ACC4(0, w3)  if (m3 & 2u) ACC4(1, w3)
        if (m3 & 4u) ACC4(2, w3)  if (m3 & 8u) ACC4(3, w3)
    }
    for (; j < cnt; j++) {
        unsigned e0 = __builtin_amdgcn_readfirstlane(lst[j]);
        float4 w0 = reinterpret_cast<const float4*>(pwt + (size_t)(e0 & 0xffffu) * C_)[ctid];
        unsigned m0 = e0 >> 16;
        if (m0 & 1u) ACC4(0, w0)  if (m0 & 2u) ACC4(1, w0)
        if (m0 & 4u) ACC4(2, w0)  if (m0 & 8u) ACC4(3, w0)
    }
#undef ACC4

    float4 inv = reinterpret_cast<const float4*>(bnc + 3072)[ctid];
    float4 sh  = reinterpret_cast<const float4*>(bnc + 3584)[ctid];
    #pragma unroll
    for (int t = 0; t < 4; t++) {
        float4 y4;
        y4.x = acc[t][0] * inv.x + sh.x;
        y4.y = acc[t][1] * inv.y + sh.y;
        y4.z = acc[t][2] * inv.z + sh.z;
        y4.w = acc[t][3] * inv.w + sh.w;
        reinterpret_cast<float4*>(y_t + (((size_t)t * B_ + b) * N_ + n) * C_)[ctid] = y4;
    }
}

// ---------------- k5: transpose back + identity add (float4 I/O) ----------------
// grid (B, C/64, N/64), block 256.
__global__ void k5_out(const float* __restrict__ y_t, const float* __restrict__ x,
                       float* __restrict__ out){
    __shared__ float tile[64 * 65];
    int b = blockIdx.x, o0 = blockIdx.y * 64, n0 = blockIdx.z * 64;
    int tid = threadIdx.x;
    for (int t = 0; t < T_; t++) {
        __syncthreads();
        #pragma unroll
        for (int i = 0; i < 4; i++) {
            int idx = i * 256 + tid;
            int o4 = idx & 15, nl = idx >> 4;      // lanes -> consecutive o (float4 read)
            float4 yv = *reinterpret_cast<const float4*>(
                y_t + (((size_t)t * B_ + b) * N_ + n0 + nl) * C_ + o0 + o4 * 4);
            tile[(o4 * 4 + 0) * 65 + nl] = yv.x;
            tile[(o4 * 4 + 1) * 65 + nl] = yv.y;
            tile[(o4 * 4 + 2) * 65 + nl] = yv.z;
            tile[(o4 * 4 + 3) * 65 + nl] = yv.w;
        }
        __syncthreads();
        #pragma unroll
        for (int i = 0; i < 4; i++) {
            int idx = i * 256 + tid;
            int n4 = idx & 15, ol = idx >> 4;      // lanes -> consecutive n (float4 write)
            size_t a = (((size_t)t * B_ + b) * C_ + o0 + ol) * N_ + n0 + n4 * 4;
            float4 xv = *reinterpret_cast<const float4*>(x + a);
            float4 yv;
            yv.x = tile[ol * 65 + n4 * 4 + 0] + xv.x;
            yv.y = tile[ol * 65 + n4 * 4 + 1] + xv.y;
            yv.z = tile[ol * 65 + n4 * 4 + 2] + xv.z;
            yv.w = tile[ol * 65 + n4 * 4 + 3] + xv.w;
            *reinterpret_cast<float4*>(out + a) = yv;
        }
    }
}

extern "C" void kernel_launch(void* const* d_in, const int* in_sizes, int n_in,
                              void* d_out, int out_size, void* d_ws, size_t ws_size,
                              hipStream_t stream){
    const float* x     = (const float*)d_in[0];
    const float* q_w   = (const float*)d_in[1];
    const float* q_g   = (const float*)d_in[2];
    const float* q_b   = (const float*)d_in[3];
    const float* q_m   = (const float*)d_in[4];
    const float* q_v   = (const float*)d_in[5];
    const float* k_w   = (const float*)d_in[6];
    const float* k_g   = (const float*)d_in[7];
    const float* k_b   = (const float*)d_in[8];
    const float* k_m   = (const float*)d_in[9];
    const float* k_v   = (const float*)d_in[10];
    const float* v_w   = (const float*)d_in[11];
    const float* v_g   = (const float*)d_in[12];
    const float* v_b   = (const float*)d_in[13];
    const float* v_m   = (const float*)d_in[14];
    const float* v_v   = (const float*)d_in[15];
    const float* pr_w  = (const float*)d_in[16];
    const float* pr_b  = (const float*)d_in[17];
    const float* p_g   = (const float*)d_in[18];
    const float* p_b2  = (const float*)d_in[19];
    const float* p_m   = (const float*)d_in[20];
    const float* p_v   = (const float*)d_in[21];
    float* out = (float*)d_out;

    char* ws = (char*)d_ws;
    float* wqkv_t          = (float*)(ws + 0);                 // 3,145,728
    float* pwt             = (float*)(ws + 3145728);           // 1,048,576
    float* bnc             = (float*)(ws + 4194304);           //    16,384
    unsigned char* xs_mask = (unsigned char*)(ws + 4210688);   // 2,097,152
    unsigned char* q_mask  = (unsigned char*)(ws + 6307840);   // 2,097,152
    unsigned char* kvand   = (unsigned char*)(ws + 8404992);   // 2,097,152
    unsigned char* kvs     = (unsigned char*)(ws + 10502144);  //     8,192
    float* y_t             = (float*)(ws + 10510336);          // 33,554,432 -> ~44 MB

    hipLaunchKernelGGL(k0_prep, dim3(258), dim3(256), 0, stream,
                       q_w, k_w, v_w, pr_w,
                       q_g,q_b,q_m,q_v, k_g,k_b,k_m,k_v, v_g,v_b,v_m,v_v,
                       p_g,p_b2,p_m,p_v, pr_b, wqkv_t, pwt, bnc);
    hipLaunchKernelGGL(k1_lif_x, dim3(B_, C_/64, N_/64), dim3(256), 0, stream,
                       x, (uint32*)xs_mask);
    hipLaunchKernelGGL(k2_qkv, dim3(N_, B_), dim3(384), 0, stream,
                       xs_mask, wqkv_t, bnc, q_mask, kvand);
    hipLaunchKernelGGL(k3_kv, dim3(B_), dim3(256), 0, stream,
                       (const uint32*)kvand, kvs);
    hipLaunchKernelGGL(k4_attn_proj, dim3(N_/2, B_), dim3(256), 0, stream,
                       q_mask, kvs, pwt, bnc, y_t);
    hipLaunchKernelGGL(k5_out, dim3(B_, C_/64, N_/64), dim3(256), 0, stream, y_t, x, out);
}

// Round 7
// 202.136 us; speedup vs baseline: 1.2524x; 1.0506x over previous
//
#include <hip/hip_runtime.h>

// SpikeDrivenTransformer block, MI355X. T=4 B=16 C=512 H=W=16 (N=256), HEADS=8.
// ALL inputs/outputs fp32. Post-LIF tensors are binary -> conv1x1 = sparse
// column-sums over an active-channel list (scalarized via readfirstlane).
// R7: kernel-count 6 -> 4 (testing ~15-20us/kernel boundary-overhead theory):
//   prep = k0 (transpose+BN fold) U k1 (x-LIF) U cnt32 zeroing
//   k2   = R6 k2 + atomic per-(b,t,ch) kv-spike counts (replaces kvand write)
//   k4   = R6 k4 + kv-LIF recompute from integer counts (replaces k3 + kvs load)
//   k5   = unchanged
// Inner loops of k2/k4 bit-identical to R6 (65us proven).

#define T_  4
#define B_  16
#define C_  512
#define N_  256
#define O3_ 1536
#define EPS_ 1e-5f

typedef unsigned int uint32;

// ---------------- prep: weight transposes + BN fold + x-LIF + counter zero ----
// bx in [0,256): 64x64 transpose tiles; [256,258): bnc fold; [258,770): x-LIF;
// [770,786): zero cnt32.
__global__ void k_prep(const float* __restrict__ qw, const float* __restrict__ kw,
                       const float* __restrict__ vw, const float* __restrict__ pw,
                       const float* qg,const float* qb,const float* qm,const float* qv,
                       const float* kg,const float* kb,const float* km,const float* kvr,
                       const float* vg,const float* vb,const float* vm,const float* vv,
                       const float* pg,const float* pb2,const float* pm,const float* pv,
                       const float* projb, const float* __restrict__ x,
                       float* __restrict__ wqkv_t, float* __restrict__ pwt,
                       float* __restrict__ bnc, uint32* __restrict__ xs_mask32,
                       uint32* __restrict__ cnt32){
    __shared__ float tile[64 * 65];
    __shared__ uint32 sm32[64 * 17];
    int bx = blockIdx.x, tid = threadIdx.x;
    if (bx < 256) {
        const float* src; float* dst; int ocol;
        int tl;
        if (bx < 192) { int g = bx / 64; tl = bx % 64;
            src = (g == 0) ? qw : (g == 1) ? kw : vw;
            dst = wqkv_t; ocol = g * 512;
        } else { tl = bx - 192; src = pw; dst = pwt; ocol = 0; }
        int o0 = (tl >> 3) * 64, c0 = (tl & 7) * 64;
        int dstride = (bx < 192) ? O3_ : C_;
        #pragma unroll
        for (int i = 0; i < 16; i++) {
            int idx = i * 256 + tid;
            int cl = idx & 63, ol = idx >> 6;      // lanes -> consecutive c (coalesced read)
            tile[ol * 65 + cl] = src[(size_t)(o0 + ol) * C_ + c0 + cl];
        }
        __syncthreads();
        #pragma unroll
        for (int i = 0; i < 16; i++) {
            int idx = i * 256 + tid;
            int ol = idx & 63, cl = idx >> 6;      // lanes -> consecutive o (coalesced write)
            dst[(size_t)(c0 + cl) * dstride + ocol + o0 + ol] = tile[ol * 65 + cl];
        }
    } else if (bx < 258) {
        int ch = (bx - 256) * 256 + tid;
        if (ch < C_) {
            {   float inv = qg[ch] / sqrtf(qv[ch] + EPS_);
                bnc[ch] = inv;            bnc[512 + ch]  = qb[ch] - qm[ch] * inv; }
            {   float inv = kg[ch] / sqrtf(kvr[ch] + EPS_);
                bnc[1024 + ch] = inv;     bnc[1536 + ch] = kb[ch] - km[ch] * inv; }
            {   float inv = vg[ch] / sqrtf(vv[ch] + EPS_);
                bnc[2048 + ch] = inv;     bnc[2560 + ch] = vb[ch] - vm[ch] * inv; }
            {   float inv = pg[ch] / sqrtf(pv[ch] + EPS_);
                float shift = pb2[ch] - pm[ch] * inv;
                bnc[3072 + ch] = inv;     bnc[3584 + ch] = projb[ch] * inv + shift; }
        }
    } else if (bx < 770) {
        int r = bx - 258;
        int b = r >> 5, rem = r & 31;
        int c0 = (rem >> 2) * 64, n0 = (rem & 3) * 64;
        #pragma unroll
        for (int i = 0; i < 4; i++) {
            int idx = i * 256 + tid;
            int nq = idx & 15, cl = idx >> 4;      // lanes -> consecutive n-quads
            const float* xp = x + ((size_t)b * C_ + c0 + cl) * N_ + n0 + nq * 4;
            float4 xv[4];
            #pragma unroll
            for (int t = 0; t < 4; t++)
                xv[t] = *reinterpret_cast<const float4*>(xp + (size_t)t * B_ * C_ * N_);
            uint32 packed = 0;
            #pragma unroll
            for (int e = 0; e < 4; e++) {
                float v = 0.f; unsigned m = 0;
                #pragma unroll
                for (int t = 0; t < 4; t++) {
                    float xt = reinterpret_cast<const float*>(&xv[t])[e];
                    v = v + (xt - v) * 0.5f;       // v += (x - v)/TAU, TAU=2
                    if (v - 1.0f >= 0.f) { m |= 1u << t; v = 0.f; }
                }
                packed |= m << (8 * e);
            }
            sm32[cl * 17 + nq] = packed;
        }
        __syncthreads();
        #pragma unroll
        for (int i = 0; i < 4; i++) {
            int idx = i * 256 + tid;
            int cq = idx & 15, nl = idx >> 4;      // lanes -> consecutive c-quads (coalesced)
            uint32 outp = 0;
            #pragma unroll
            for (int e = 0; e < 4; e++) {
                uint32 wv = sm32[(cq * 4 + e) * 17 + (nl >> 2)];
                outp |= ((wv >> (8 * (nl & 3))) & 0xffu) << (8 * e);
            }
            xs_mask32[((size_t)b * N_ + n0 + nl) * 128 + (c0 >> 2) + cq] = outp;
        }
    } else {
        int idx = (bx - 770) * 256 + tid;          // 4096 uint32 counters
        cnt32[idx] = 0;
    }
}

// ---------------- k2: sparse qkv GEMM + BN + LIF + atomic kv counts ----------
// grid (N, B), block 384. Thread tid: group g=tid>>7 (q/k/v), owns 4 channels;
// one float4 per active row (384 lanes x 16B = full 6KB q|k|v row). Unroll-4.
__global__ __launch_bounds__(384) void
k2_qkv(const unsigned char* __restrict__ xs_mask,
       const float* __restrict__ wqkv_t,
       const float* __restrict__ bnc,
       unsigned char* __restrict__ q_mask,
       uint32* __restrict__ cnt32){
    __shared__ uint32 smask[128];                  // 512 bytes; reused as kbits buffer
    __shared__ uint32 scnt;
    __shared__ uint32 slist[512];
    int n = blockIdx.x, b = blockIdx.y, tid = threadIdx.x;
    size_t colbase = ((size_t)b * N_ + n) * C_;
    if (tid < 128) smask[tid] = reinterpret_cast<const uint32*>(xs_mask + colbase)[tid];
    if (tid == 0) scnt = 0;
    __syncthreads();
    if (tid < 256) {
        const unsigned char* smb = (const unsigned char*)smask;
        #pragma unroll
        for (int h = 0; h < 2; h++) {
            int c = tid + (h << 8);
            unsigned m = smb[c];
            if (m) { unsigned p = atomicAdd(&scnt, 1u); slist[p] = (unsigned)c | (m << 16); }
        }
    }
    __syncthreads();
    int cnt = scnt;

    int g = tid >> 7;                              // 0=q, 1=k, 2=v
    float acc[4][4];
    #pragma unroll
    for (int t = 0; t < 4; t++)
        #pragma unroll
        for (int i = 0; i < 4; i++) acc[t][i] = 0.f;

#define ACC4(t, w_) { acc[t][0]+=w_.x; acc[t][1]+=w_.y; acc[t][2]+=w_.z; acc[t][3]+=w_.w; }
    int j = 0;
    for (; j + 4 <= cnt; j += 4) {
        unsigned e0 = __builtin_amdgcn_readfirstlane(slist[j]);
        unsigned e1 = __builtin_amdgcn_readfirstlane(slist[j + 1]);
        unsigned e2 = __builtin_amdgcn_readfirstlane(slist[j + 2]);
        unsigned e3 = __builtin_amdgcn_readfirstlane(slist[j + 3]);
        float4 w0 = reinterpret_cast<const float4*>(wqkv_t + (size_t)(e0 & 0xffffu) * O3_)[tid];
        float4 w1 = reinterpret_cast<const float4*>(wqkv_t + (size_t)(e1 & 0xffffu) * O3_)[tid];
        float4 w2 = reinterpret_cast<const float4*>(wqkv_t + (size_t)(e2 & 0xffffu) * O3_)[tid];
        float4 w3 = reinterpret_cast<const float4*>(wqkv_t + (size_t)(e3 & 0xffffu) * O3_)[tid];
        unsigned m0 = e0 >> 16, m1 = e1 >> 16, m2 = e2 >> 16, m3 = e3 >> 16;
        if (m0 & 1u) ACC4(0, w0)  if (m0 & 2u) ACC4(1, w0)
        if (m0 & 4u) ACC4(2, w0)  if (m0 & 8u) ACC4(3, w0)
        if (m1 & 1u) ACC4(0, w1)  if (m1 & 2u) ACC4(1, w1)
        if (m1 & 4u) ACC4(2, w1)  if (m1 & 8u) ACC4(3, w1)
        if (m2 & 1u) ACC4(0, w2)  if (m2 & 2u) ACC4(1, w2)
        if (m2 & 4u) ACC4(2, w2)  if (m2 & 8u) ACC4(3, w2)
        if (m3 & 1u) ACC4(0, w3)  if (m3 & 2u) ACC4(1, w3)
        if (m3 & 4u) ACC4(2, w3)  if (m3 & 8u) ACC4(3, w3)
    }
    for (; j < cnt; j++) {
        unsigned e0 = __builtin_amdgcn_readfirstlane(slist[j]);
        float4 w0 = reinterpret_cast<const float4*>(wqkv_t + (size_t)(e0 & 0xffffu) * O3_)[tid];
        unsigned m0 = e0 >> 16;
        if (m0 & 1u) ACC4(0, w0)  if (m0 & 2u) ACC4(1, w0)
        if (m0 & 4u) ACC4(2, w0)  if (m0 & 8u) ACC4(3, w0)
    }
#undef ACC4

    // BN + LIF per owned channel; pack 4 channel-bytes into one uint.
    int chb = (tid & 127) * 4;
    unsigned packed = 0;
    #pragma unroll
    for (int i = 0; i < 4; i++) {
        int ch = chb + i;
        float inv = bnc[g * 1024 + ch];
        float sh  = bnc[g * 1024 + 512 + ch];
        float v = 0.f; unsigned bits = 0;
        #pragma unroll
        for (int t = 0; t < 4; t++) {
            float pre = acc[t][i] * inv + sh;      // BN
            v = v + (pre - v) * 0.5f;              // LIF
            if (v - 1.0f >= 0.f) { bits |= 1u << t; v = 0.f; }
        }
        packed |= bits << (8 * i);
    }
    if (g == 0)      reinterpret_cast<uint32*>(q_mask + colbase)[tid] = packed;
    else if (g == 1) smask[tid - 128] = packed;    // kbits exchange
    __syncthreads();
    if (g == 2) {
        unsigned kb = smask[tid - 256];
        unsigned kv = packed & kb;                 // 4 ch x 4 t-bits (byte each)
        if (kv) {
            uint32* cbase = cnt32 + b * 1024 + (chb >> 1);   // [b][t][c-pair]
            #pragma unroll
            for (int t = 0; t < 4; t++) {
                unsigned v01 = ((kv >> t) & 1u) | (((kv >> (8 + t)) & 1u) << 16);
                unsigned v23 = ((kv >> (16 + t)) & 1u) | (((kv >> (24 + t)) & 1u) << 16);
                if (v01) atomicAdd(cbase + t * 256, v01);
                if (v23) atomicAdd(cbase + t * 256 + 1, v23);
            }
        }
    }
}

// ---------------- k4: kv-LIF from counts + sparse proj GEMM + BN -------------
// grid (N/2, B), block 256 = 2 columns x 128 threads (col = tid>>7, wave-uniform).
// Thread owns 4 channels (float4 per 2KB row), unroll-4.
__global__ __launch_bounds__(256) void
k4_attn_proj(const unsigned char* __restrict__ q_mask,
             const uint32* __restrict__ cnt32,
             const float* __restrict__ pwt,
             const float* __restrict__ bnc,
             float* __restrict__ y_t){
    __shared__ uint32 smask[2][128];
    __shared__ uint32 scnt[2];
    __shared__ uint32 slist[2][512];
    int b = blockIdx.y, tid = threadIdx.x;
    int col = tid >> 7, ctid = tid & 127;
    int n = blockIdx.x * 2 + col;
    size_t colbase = ((size_t)b * N_ + n) * C_;
    // recompute kv-LIF from integer counts (replaces k3; exact: halvings of ints)
    unsigned kvs_packed = 0;
    {
        const uint32* cbase = cnt32 + b * 1024 + ctid * 2;
        uint32 c01[4], c23[4];
        #pragma unroll
        for (int t = 0; t < 4; t++) { c01[t] = cbase[t * 256]; c23[t] = cbase[t * 256 + 1]; }
        #pragma unroll
        for (int e = 0; e < 4; e++) {
            float v = 0.f; unsigned bits = 0;
            #pragma unroll
            for (int t = 0; t < 4; t++) {
                uint32 pair = (e < 2) ? c01[t] : c23[t];
                float cn = (float)(int)((e & 1) ? (pair >> 16) : (pair & 0xffffu));
                v = v + (cn - v) * 0.5f;
                if (v - 0.5f >= 0.f) { bits |= 1u << t; v = 0.f; }
            }
            kvs_packed |= bits << (8 * e);
        }
    }
    {
        uint32 qm = reinterpret_cast<const uint32*>(q_mask + colbase)[ctid];
        smask[col][ctid] = qm & kvs_packed;
    }
    if (ctid == 0) scnt[col] = 0;
    __syncthreads();
    {
        const unsigned char* smb = (const unsigned char*)smask[col];
        #pragma unroll
        for (int h = 0; h < 4; h++) {
            int c = ctid * 4 + h;
            unsigned m = smb[c];
            if (m) { unsigned p = atomicAdd(&scnt[col], 1u); slist[col][p] = (unsigned)c | (m << 16); }
        }
    }
    __syncthreads();
    int cnt = scnt[col];
    const uint32* lst = slist[col];

    float acc[4][4];
    #pragma unroll
    for (int t = 0; t < 4; t++)
        #pragma unroll
        for (int i = 0; i < 4; i++) acc[t][i] = 0.f;

#define ACC4(t, w_) { acc[t][0]+=w_.x; acc[t][1]+=w_.y; acc[t][2]+=w_.z; acc[t][3]+=w_.w; }
    int j = 0;
    for (; j + 4 <= cnt; j += 4) {
        unsigned e0 = __builtin_amdgcn_readfirstlane(lst[j]);
        unsigned e1 = __builtin_amdgcn_readfirstlane(lst[j + 1]);
        unsigned e2 = __builtin_amdgcn_readfirstlane(lst[j + 2]);
        unsigned e3 = __builtin_amdgcn_readfirstlane(lst[j + 3]);
        float4 w0 = reinterpret_cast<const float4*>(pwt + (size_t)(e0 & 0xffffu) * C_)[ctid];
        float4 w1 = reinterpret_cast<const float4*>(pwt + (size_t)(e1 & 0xffffu) * C_)[ctid];
        float4 w2 = reinterpret_cast<const float4*>(pwt + (size_t)(e2 & 0xffffu) * C_)[ctid];
        float4 w3 = reinterpret_cast<const float4*>(pwt + (size_t)(e3 & 0xffffu) * C_)[ctid];
        unsigned m0 = e0 >> 16, m1 = e1 >> 16, m2 = e2 >> 16, m3 = e3 >> 16;
        if (m0 & 1u) ACC4(0, w0)  if (m0 & 2u) ACC4(1, w0)
        if (m0 & 4u) ACC4(2, w0)  if (m0 & 8u) ACC4(3, w0)
        if (m1 & 1u) ACC4(0, w1)  if (m1 & 2u) ACC4(1, w1)
        if (m1 & 4u) ACC4(2, w1)  if (m1 & 8u) ACC4(3, w1)
        if (m2 & 1u) ACC4(0, w2)  if (m2 & 2u) ACC4(1, w2)
        if (m2 & 4u) ACC4(2, w2)  if (m2 & 8u) ACC4(3, w2)
        if (m3 & 1u) ACC4(0, w3)  if (m3 & 2u) ACC4(1, w3)
        if (m3 & 4u) ACC4(2, w3)  if (m3 & 8u) ACC4(3, w3)
    }
    for (; j < cnt; j++) {
        unsigned e0 = __builtin_amdgcn_readfirstlane(lst[j]);
        float4 w0 = reinterpret_cast<const float4*>(pwt + (size_t)(e0 & 0xffffu) * C_)[ctid];
        unsigned m0 = e0 >> 16;
        if (m0 & 1u) ACC4(0, w0)  if (m0 & 2u) ACC4(1, w0)
        if (m0 & 4u) ACC4(2, w0)  if (m0 & 8u) ACC4(3, w0)
    }
#undef ACC4

    float4 inv = reinterpret_cast<const float4*>(bnc + 3072)[ctid];
    float4 sh  = reinterpret_cast<const float4*>(bnc + 3584)[ctid];
    #pragma unroll
    for (int t = 0; t < 4; t++) {
        float4 y4;
        y4.x = acc[t][0] * inv.x + sh.x;
        y4.y = acc[t][1] * inv.y + sh.y;
        y4.z = acc[t][2] * inv.z + sh.z;
        y4.w = acc[t][3] * inv.w + sh.w;
        reinterpret_cast<float4*>(y_t + (((size_t)t * B_ + b) * N_ + n) * C_)[ctid] = y4;
    }
}

// ---------------- k5: transpose back + identity add (float4 I/O) ----------------
// grid (B, C/64, N/64), block 256.
__global__ void k5_out(const float* __restrict__ y_t, const float* __restrict__ x,
                       float* __restrict__ out){
    __shared__ float tile[64 * 65];
    int b = blockIdx.x, o0 = blockIdx.y * 64, n0 = blockIdx.z * 64;
    int tid = threadIdx.x;
    for (int t = 0; t < T_; t++) {
        __syncthreads();
        #pragma unroll
        for (int i = 0; i < 4; i++) {
            int idx = i * 256 + tid;
            int o4 = idx & 15, nl = idx >> 4;      // lanes -> consecutive o (float4 read)
            float4 yv = *reinterpret_cast<const float4*>(
                y_t + (((size_t)t * B_ + b) * N_ + n0 + nl) * C_ + o0 + o4 * 4);
            tile[(o4 * 4 + 0) * 65 + nl] = yv.x;
            tile[(o4 * 4 + 1) * 65 + nl] = yv.y;
            tile[(o4 * 4 + 2) * 65 + nl] = yv.z;
            tile[(o4 * 4 + 3) * 65 + nl] = yv.w;
        }
        __syncthreads();
        #pragma unroll
        for (int i = 0; i < 4; i++) {
            int idx = i * 256 + tid;
            int n4 = idx & 15, ol = idx >> 4;      // lanes -> consecutive n (float4 write)
            size_t a = (((size_t)t * B_ + b) * C_ + o0 + ol) * N_ + n0 + n4 * 4;
            float4 xv = *reinterpret_cast<const float4*>(x + a);
            float4 yv;
            yv.x = tile[ol * 65 + n4 * 4 + 0] + xv.x;
            yv.y = tile[ol * 65 + n4 * 4 + 1] + xv.y;
            yv.z = tile[ol * 65 + n4 * 4 + 2] + xv.z;
            yv.w = tile[ol * 65 + n4 * 4 + 3] + xv.w;
            *reinterpret_cast<float4*>(out + a) = yv;
        }
    }
}

extern "C" void kernel_launch(void* const* d_in, const int* in_sizes, int n_in,
                              void* d_out, int out_size, void* d_ws, size_t ws_size,
                              hipStream_t stream){
    const float* x     = (const float*)d_in[0];
    const float* q_w   = (const float*)d_in[1];
    const float* q_g   = (const float*)d_in[2];
    const float* q_b   = (const float*)d_in[3];
    const float* q_m   = (const float*)d_in[4];
    const float* q_v   = (const float*)d_in[5];
    const float* k_w   = (const float*)d_in[6];
    const float* k_g   = (const float*)d_in[7];
    const float* k_b   = (const float*)d_in[8];
    const float* k_m   = (const float*)d_in[9];
    const float* k_v   = (const float*)d_in[10];
    const float* v_w   = (const float*)d_in[11];
    const float* v_g   = (const float*)d_in[12];
    const float* v_b   = (const float*)d_in[13];
    const float* v_m   = (const float*)d_in[14];
    const float* v_v   = (const float*)d_in[15];
    const float* pr_w  = (const float*)d_in[16];
    const float* pr_b  = (const float*)d_in[17];
    const float* p_g   = (const float*)d_in[18];
    const float* p_b2  = (const float*)d_in[19];
    const float* p_m   = (const float*)d_in[20];
    const float* p_v   = (const float*)d_in[21];
    float* out = (float*)d_out;

    char* ws = (char*)d_ws;
    float* wqkv_t          = (float*)(ws + 0);                 // 3,145,728
    float* pwt             = (float*)(ws + 3145728);           // 1,048,576
    float* bnc             = (float*)(ws + 4194304);           //    16,384
    unsigned char* xs_mask = (unsigned char*)(ws + 4210688);   // 2,097,152
    unsigned char* q_mask  = (unsigned char*)(ws + 6307840);   // 2,097,152
    uint32* cnt32          = (uint32*)(ws + 8404992);          //    16,384
    float* y_t             = (float*)(ws + 8421376);           // 33,554,432 -> ~42 MB

    hipLaunchKernelGGL(k_prep, dim3(786), dim3(256), 0, stream,
                       q_w, k_w, v_w, pr_w,
                       q_g,q_b,q_m,q_v, k_g,k_b,k_m,k_v, v_g,v_b,v_m,v_v,
                       p_g,p_b2,p_m,p_v, pr_b, x,
                       wqkv_t, pwt, bnc, (uint32*)xs_mask, cnt32);
    hipLaunchKernelGGL(k2_qkv, dim3(N_, B_), dim3(384), 0, stream,
                       xs_mask, wqkv_t, bnc, q_mask, cnt32);
    hipLaunchKernelGGL(k4_attn_proj, dim3(N_/2, B_), dim3(256), 0, stream,
                       q_mask, cnt32, pwt, bnc, y_t);
    hipLaunchKernelGGL(k5_out, dim3(B_, C_/64, N_/64), dim3(256), 0, stream, y_t, x, out);
}